// Round 2
// baseline (546.389 us; speedup 1.0000x reference)
//
#include <hip/hip_runtime.h>

// Fused RK4 step for 2D Burgers-like PDE, periodic BCs, radius-2 stencils.
// R4 (retry; R1 bench was a container-level infra failure, kernel unchanged):
//  - Padless row-contiguous 80x96 tile per field (LCOLS=96 -> row stride == 0
//    mod 32 banks: uniform bank rotation per row, kills the ds_read conflicts
//    that LCOLS=88's 24-bank/row rotation caused).
//  - Staging via __builtin_amdgcn_global_load_lds (60 async 1024B chunks per
//    block; per-lane wrapped global source, linear LDS dest) -- no VGPR
//    round-trip, no zero-pad init.
//  - Exact (non-rounded) per-stage col regions on the 96-wide slab:
//    5064 quad-stages/tile vs 5480 before (-7.6% VALU work).
//  - __launch_bounds__(1024,8) pins VGPR<=64 -> 2 blocks/CU residency kept.

typedef float f4 __attribute__((ext_vector_type(4)));
typedef float f2 __attribute__((ext_vector_type(2)));

#define LCOLS 96            // output cols at staged cols [16,80)
#define LROWS 80            // output rows at staged rows [8,72)
#define NBUF  (LROWS*LCOLS) // 7680 floats = 30720 B per field
#define NT    1024
#define NQ    2             // 1600 quads / 1024 threads

#define GLOAD16(gp, lp) __builtin_amdgcn_global_load_lds(                      \
    (const __attribute__((address_space(1))) void*)(gp),                       \
    (__attribute__((address_space(3))) void*)(lp), 16, 0, 0)

__global__ __launch_bounds__(NT, 8)
void rk4_stencil(const float* __restrict__ h,
                 const float* __restrict__ sRe, const float* __restrict__ sUA,
                 const float* __restrict__ sUB, const float* __restrict__ sVA,
                 const float* __restrict__ sVB, float* __restrict__ out)
{
    __shared__ __align__(16) float tu[NBUF];
    __shared__ __align__(16) float tv[NBUF];

    const int tid = threadIdx.x;
    const int tc = blockIdx.x, tr = blockIdx.y, bb = blockIdx.z;

    const float Re = sRe[0], UA = sUA[0], UB = sUB[0], VA = sVA[0], VB = sVB[0];
    const float nu = 0.001f / Re;

    const float d1 = 800.f/12.f;          // (8/12)/DX
    const float d2 = 100.f/12.f;          // (1/12)/DX
    const float a1 = (4.f/3.f)*1.0e4f;    // (4/3)/DX^2
    const float a2 = -(1.f/12.f)*1.0e4f;  // (-1/12)/DX^2
    const float a0 = -5.0e4f;             // -5/DX^2 (both axes center)

    const f4 z4 = {0.f, 0.f, 0.f, 0.f};

    const size_t plane = 1048576;
    const float* uin = h + (size_t)(bb*2) * plane;
    const float* vin = uin + plane;
    const int base_r = tr*64 - 8  + 1024;   // pre-biased for & 1023 wrap
    const int base_c = tc*64 - 16 + 1024;   // multiple of 16 -> no f4 straddle

    // ---- async stage u0,v0: 2 fields x 30 chunks x 1024B (row-contiguous) ----
    {
        const int wave = tid >> 6, lane = tid & 63;
#pragma unroll
        for (int it = 0; it < 4; ++it) {
            int c = wave + 16*it;           // wave-uniform chunk id 0..63
            if (c < 60) {
                int fld = (c >= 30);
                int cc  = fld ? (c - 30) : c;
                int idx = 256*cc + 4*lane;  // float index into 80x96 tile
                int row = idx / LCOLS;
                int col = idx - row*LCOLS;
                int gr = (base_r + row) & 1023;
                int gc = (base_c + col) & 1023;
                const float* gp = (fld ? vin : uin) + ((size_t)gr << 10) + gc;
                float* lp = (fld ? tv : tu) + 256*cc;   // wave-uniform LDS base
                GLOAD16(gp, lp);
            }
        }
    }
    __syncthreads();   // drains vmcnt -> tile visible

    // ownership: quad q = tid + NT*j ; row qr = q/20, col quad qcA = 2 + q%20
    int  lidx[NQ]; bool has[NQ]; int qrA[NQ], qcA[NQ];
    f4 ku[NQ], kv[NQ], au[NQ], av[NQ];   // prev-stage k and RK accumulator
#pragma unroll
    for (int j = 0; j < NQ; ++j) {
        int q = tid + NT*j;
        has[j] = (j == 0) || (q < 1600);
        int qr = q / 20, qc = q - qr*20 + 2;
        qrA[j] = qr; qcA[j] = qc;
        lidx[j] = qr*LCOLS + 4*qc;
        ku[j] = z4; kv[j] = z4; au[j] = z4; av[j] = z4;
    }

    // exact per-stage regions (output = staged rows [8,72) x cols [16,80)):
    // k1 rows [2,78) qc [2,22); k2 rows [4,76) qc [3,21);
    // k3 rows [6,74) qc [3,21); k4 rows [8,72) qc [4,20)
    const int rowlo[4] = {2, 4, 6, 8};
    const int rowhi[4] = {78, 76, 74, 72};
    const int qclo[4]  = {2, 3, 3, 4};
    const int qchi[4]  = {22, 21, 21, 20};
    const float csub_t[4] = {0.f, 0.25f, 0.25f, 0.5f};  // c_{s-1}: undo prev update
    const float cadd_t[4] = {0.25f, 0.25f, 0.5f, 0.f};  // c_s: apply this update
    const float wgt_t[4]  = {1.f, 2.f, 2.f, 1.f};

    float* outu = out + (size_t)(bb*2) * plane;
    float* outv = outu + plane;

#pragma unroll
    for (int s = 0; s < 4; ++s) {
        const float wgt  = wgt_t[s];
        const float csub = csub_t[s];
        const float cadd = cadd_t[s];
        f4 stu[NQ], stv[NQ];
        bool act[NQ];
#pragma unroll
        for (int j = 0; j < NQ; ++j) {
            act[j] = has[j] && qrA[j] >= rowlo[s] && qrA[j] < rowhi[s]
                            && qcA[j] >= qclo[s]  && qcA[j] < qchi[s];
            if (!act[j]) continue;
            const int l = lidx[j];
            f4 ucc = *(const f4*)(tu+l);
            f2 ul2 = *(const f2*)(tu+l-2);
            f2 ur2 = *(const f2*)(tu+l+4);
            f4 un1 = *(const f4*)(tu+l-LCOLS);
            f4 us1 = *(const f4*)(tu+l+LCOLS);
            f4 un2 = *(const f4*)(tu+l-2*LCOLS);
            f4 us2 = *(const f4*)(tu+l+2*LCOLS);
            f4 vcc = *(const f4*)(tv+l);
            f2 vl2 = *(const f2*)(tv+l-2);
            f2 vr2 = *(const f2*)(tv+l+4);
            f4 vn1 = *(const f4*)(tv+l-LCOLS);
            f4 vs1 = *(const f4*)(tv+l+LCOLS);
            f4 vn2 = *(const f4*)(tv+l-2*LCOLS);
            f4 vs2 = *(const f4*)(tv+l+2*LCOLS);
            float hu[8] = {ul2[0],ul2[1],ucc[0],ucc[1],ucc[2],ucc[3],ur2[0],ur2[1]};
            float hv[8] = {vl2[0],vl2[1],vcc[0],vcc[1],vcc[2],vcc[3],vr2[0],vr2[1]};
            f4 ou, ov;   // stage-3 output staging
#pragma unroll
            for (int k = 0; k < 4; ++k) {
                float u = hu[k+2], v = hv[k+2];
                // row-direction derivative (axis 2) = reference K_DX
                float urow = d1*(us1[k]-un1[k]) + d2*(un2[k]-us2[k]);
                float vrow = d1*(vs1[k]-vn1[k]) + d2*(vn2[k]-vs2[k]);
                // col-direction derivative (axis 3) = reference K_DY
                float ucol = d1*(hu[k+3]-hu[k+1]) + d2*(hu[k]-hu[k+4]);
                float vcol = d1*(hv[k+3]-hv[k+1]) + d2*(hv[k]-hv[k+4]);
                float ulap = a1*((un1[k]+us1[k])+(hu[k+1]+hu[k+3]))
                           + a2*((un2[k]+us2[k])+(hu[k]+hu[k+4])) + a0*u;
                float vlap = a1*((vn1[k]+vs1[k])+(hv[k+1]+hv[k+3]))
                           + a2*((vn2[k]+vs2[k])+(hv[k]+hv[k+4])) + a0*v;
                float fu = nu*ulap + UA*(u*urow) + UB*(v*ucol);
                float fv = nu*vlap + VA*(u*vrow) + VB*(v*vcol);
                float kuold = ku[j][k], kvold = kv[j][k];
                if (s == 3) {
                    // u0 = t3 - DT*k3 ; out = u0 + (DT/6)*(k1+2k2+2k3+k4)
                    ou[k] = (u - 0.5f*kuold) + (1.f/12.f)*(au[j][k] + fu);
                    ov[k] = (v - 0.5f*kvold) + (1.f/12.f)*(av[j][k] + fv);
                } else {
                    au[j][k] += wgt*fu;
                    av[j][k] += wgt*fv;
                    // t_{s+1} = u0 + cadd*k_new, with u0 = t_s - csub*k_prev
                    stu[j][k] = (u - csub*kuold) + cadd*fu;
                    stv[j][k] = (v - csub*kvold) + cadd*fv;
                    ku[j][k] = fu;
                    kv[j][k] = fv;
                }
            }
            if (s == 3) {
                int gr = tr*64 + qrA[j] - 8;          // qr in [8,72) -> [0,64)
                int gc = tc*64 + 4*qcA[j] - 16;       // qc in [4,20) -> [0,64)
                __builtin_nontemporal_store(ou, (f4*)(outu + (size_t)gr*1024 + gc));
                __builtin_nontemporal_store(ov, (f4*)(outv + (size_t)gr*1024 + gc));
            }
        }
        if (s < 3) {
            __syncthreads();   // all reads of t_s done
#pragma unroll
            for (int j = 0; j < NQ; ++j) {
                if (!act[j]) continue;
                *(f4*)(tu+lidx[j]) = stu[j];
                *(f4*)(tv+lidx[j]) = stv[j];
            }
            __syncthreads();   // t_{s+1} visible
        }
    }
}

extern "C" void kernel_launch(void* const* d_in, const int* in_sizes, int n_in,
                              void* d_out, int out_size, void* d_ws, size_t ws_size,
                              hipStream_t stream) {
    const float* h   = (const float*)d_in[0];
    const float* sRe = (const float*)d_in[1];
    const float* sUA = (const float*)d_in[2];
    const float* sUB = (const float*)d_in[3];
    const float* sVA = (const float*)d_in[4];
    const float* sVB = (const float*)d_in[5];
    float* o = (float*)d_out;
    rk4_stencil<<<dim3(16,16,8), dim3(NT,1,1), 0, stream>>>(h, sRe, sUA, sUB, sVA, sVB, o);
}

// Round 3
// 210.125 us; speedup vs baseline: 2.6003x; 2.6003x over previous
//
#include <hip/hip_runtime.h>

// Fused RK4 step for 2D Burgers-like PDE, periodic BCs, radius-2 stencils.
// R5: R4 with the spill catastrophe fixed + center-in-register.
//  - __launch_bounds__(1024,4): VGPR cap 128 (body needs ~60; R4's (1024,8)
//    forced VGPR<=64, compiler hit 32 and spilled all RK state -> 10x HBM).
//  - Padless row-contiguous 80x96 tile per field, async global_load_lds
//    staging (60 x 1024B chunks), exact per-stage regions  [validated in R4].
//  - NEW: center values t_s carried in registers across stages (stu/stv);
//    only stage 0 reads the center from LDS. Regions shrink monotonically so
//    every stage-(s+1)-active quad has a valid stage-s register center.
//    -17% LDS read bytes, 2 fewer lgkm deps per quad-stage, 0 extra VGPRs.

typedef float f4 __attribute__((ext_vector_type(4)));
typedef float f2 __attribute__((ext_vector_type(2)));

#define LCOLS 96            // output cols at staged cols [16,80)
#define LROWS 80            // output rows at staged rows [8,72)
#define NBUF  (LROWS*LCOLS) // 7680 floats = 30720 B per field
#define NT    1024
#define NQ    2             // 1600 quads / 1024 threads

#define GLOAD16(gp, lp) __builtin_amdgcn_global_load_lds(                      \
    (const __attribute__((address_space(1))) void*)(gp),                       \
    (__attribute__((address_space(3))) void*)(lp), 16, 0, 0)

__global__ __launch_bounds__(NT, 4)
void rk4_stencil(const float* __restrict__ h,
                 const float* __restrict__ sRe, const float* __restrict__ sUA,
                 const float* __restrict__ sUB, const float* __restrict__ sVA,
                 const float* __restrict__ sVB, float* __restrict__ out)
{
    __shared__ __align__(16) float tu[NBUF];
    __shared__ __align__(16) float tv[NBUF];

    const int tid = threadIdx.x;
    const int tc = blockIdx.x, tr = blockIdx.y, bb = blockIdx.z;

    const float Re = sRe[0], UA = sUA[0], UB = sUB[0], VA = sVA[0], VB = sVB[0];
    const float nu = 0.001f / Re;

    const float d1 = 800.f/12.f;          // (8/12)/DX
    const float d2 = 100.f/12.f;          // (1/12)/DX
    const float a1 = (4.f/3.f)*1.0e4f;    // (4/3)/DX^2
    const float a2 = -(1.f/12.f)*1.0e4f;  // (-1/12)/DX^2
    const float a0 = -5.0e4f;             // -5/DX^2 (both axes center)

    const f4 z4 = {0.f, 0.f, 0.f, 0.f};

    const size_t plane = 1048576;
    const float* uin = h + (size_t)(bb*2) * plane;
    const float* vin = uin + plane;
    const int base_r = tr*64 - 8  + 1024;   // pre-biased for & 1023 wrap
    const int base_c = tc*64 - 16 + 1024;   // multiple of 16 -> no f4 straddle

    // ---- async stage u0,v0: 2 fields x 30 chunks x 1024B (row-contiguous) ----
    {
        const int wave = tid >> 6, lane = tid & 63;
#pragma unroll
        for (int it = 0; it < 4; ++it) {
            int c = wave + 16*it;           // wave-uniform chunk id 0..63
            if (c < 60) {
                int fld = (c >= 30);
                int cc  = fld ? (c - 30) : c;
                int idx = 256*cc + 4*lane;  // float index into 80x96 tile
                int row = idx / LCOLS;
                int col = idx - row*LCOLS;
                int gr = (base_r + row) & 1023;
                int gc = (base_c + col) & 1023;
                const float* gp = (fld ? vin : uin) + ((size_t)gr << 10) + gc;
                float* lp = (fld ? tv : tu) + 256*cc;   // wave-uniform LDS base
                GLOAD16(gp, lp);
            }
        }
    }
    __syncthreads();   // drains vmcnt -> tile visible

    // ownership: quad q = tid + NT*j ; row qr = q/20, col quad qcA = 2 + q%20
    int  lidx[NQ]; bool has[NQ]; int qrA[NQ], qcA[NQ];
    f4 ku[NQ], kv[NQ], au[NQ], av[NQ];   // prev-stage k and RK accumulator
    f4 stu[NQ], stv[NQ];                 // t_{s+1} center: LDS-write staging AND
                                         // next stage's in-register center
#pragma unroll
    for (int j = 0; j < NQ; ++j) {
        int q = tid + NT*j;
        has[j] = (j == 0) || (q < 1600);
        int qr = q / 20, qc = q - qr*20 + 2;
        qrA[j] = qr; qcA[j] = qc;
        lidx[j] = qr*LCOLS + 4*qc;
        ku[j] = z4; kv[j] = z4; au[j] = z4; av[j] = z4;
        stu[j] = z4; stv[j] = z4;
    }

    // exact per-stage regions (output = staged rows [8,72) x cols [16,80)):
    // k1 rows [2,78) qc [2,22); k2 rows [4,76) qc [3,21);
    // k3 rows [6,74) qc [3,21); k4 rows [8,72) qc [4,20)
    // regions shrink monotonically -> register center valid for s>=1.
    const int rowlo[4] = {2, 4, 6, 8};
    const int rowhi[4] = {78, 76, 74, 72};
    const int qclo[4]  = {2, 3, 3, 4};
    const int qchi[4]  = {22, 21, 21, 20};
    const float csub_t[4] = {0.f, 0.25f, 0.25f, 0.5f};  // c_{s-1}: undo prev update
    const float cadd_t[4] = {0.25f, 0.25f, 0.5f, 0.f};  // c_s: apply this update
    const float wgt_t[4]  = {1.f, 2.f, 2.f, 1.f};

    float* outu = out + (size_t)(bb*2) * plane;
    float* outv = outu + plane;

#pragma unroll
    for (int s = 0; s < 4; ++s) {
        const float wgt  = wgt_t[s];
        const float csub = csub_t[s];
        const float cadd = cadd_t[s];
        bool act[NQ];
#pragma unroll
        for (int j = 0; j < NQ; ++j) {
            act[j] = has[j] && qrA[j] >= rowlo[s] && qrA[j] < rowhi[s]
                            && qcA[j] >= qclo[s]  && qcA[j] < qchi[s];
            if (!act[j]) continue;
            const int l = lidx[j];
            f4 ucc, vcc;
            if (s == 0) { ucc = *(const f4*)(tu+l); vcc = *(const f4*)(tv+l); }
            else        { ucc = stu[j];             vcc = stv[j]; }
            f2 ul2 = *(const f2*)(tu+l-2);
            f2 ur2 = *(const f2*)(tu+l+4);
            f4 un1 = *(const f4*)(tu+l-LCOLS);
            f4 us1 = *(const f4*)(tu+l+LCOLS);
            f4 un2 = *(const f4*)(tu+l-2*LCOLS);
            f4 us2 = *(const f4*)(tu+l+2*LCOLS);
            f2 vl2 = *(const f2*)(tv+l-2);
            f2 vr2 = *(const f2*)(tv+l+4);
            f4 vn1 = *(const f4*)(tv+l-LCOLS);
            f4 vs1 = *(const f4*)(tv+l+LCOLS);
            f4 vn2 = *(const f4*)(tv+l-2*LCOLS);
            f4 vs2 = *(const f4*)(tv+l+2*LCOLS);
            float hu[8] = {ul2[0],ul2[1],ucc[0],ucc[1],ucc[2],ucc[3],ur2[0],ur2[1]};
            float hv[8] = {vl2[0],vl2[1],vcc[0],vcc[1],vcc[2],vcc[3],vr2[0],vr2[1]};
            f4 ou, ov;   // stage-3 output staging
#pragma unroll
            for (int k = 0; k < 4; ++k) {
                float u = hu[k+2], v = hv[k+2];
                // row-direction derivative (axis 2) = reference K_DX
                float urow = d1*(us1[k]-un1[k]) + d2*(un2[k]-us2[k]);
                float vrow = d1*(vs1[k]-vn1[k]) + d2*(vn2[k]-vs2[k]);
                // col-direction derivative (axis 3) = reference K_DY
                float ucol = d1*(hu[k+3]-hu[k+1]) + d2*(hu[k]-hu[k+4]);
                float vcol = d1*(hv[k+3]-hv[k+1]) + d2*(hv[k]-hv[k+4]);
                float ulap = a1*((un1[k]+us1[k])+(hu[k+1]+hu[k+3]))
                           + a2*((un2[k]+us2[k])+(hu[k]+hu[k+4])) + a0*u;
                float vlap = a1*((vn1[k]+vs1[k])+(hv[k+1]+hv[k+3]))
                           + a2*((vn2[k]+vs2[k])+(hv[k]+hv[k+4])) + a0*v;
                float fu = nu*ulap + UA*(u*urow) + UB*(v*ucol);
                float fv = nu*vlap + VA*(u*vrow) + VB*(v*vcol);
                float kuold = ku[j][k], kvold = kv[j][k];
                if (s == 3) {
                    // u0 = t3 - DT*k3 ; out = u0 + (DT/6)*(k1+2k2+2k3+k4)
                    ou[k] = (u - 0.5f*kuold) + (1.f/12.f)*(au[j][k] + fu);
                    ov[k] = (v - 0.5f*kvold) + (1.f/12.f)*(av[j][k] + fv);
                } else {
                    au[j][k] += wgt*fu;
                    av[j][k] += wgt*fv;
                    // t_{s+1} = u0 + cadd*k_new, with u0 = t_s - csub*k_prev
                    stu[j][k] = (u - csub*kuold) + cadd*fu;
                    stv[j][k] = (v - csub*kvold) + cadd*fv;
                    ku[j][k] = fu;
                    kv[j][k] = fv;
                }
            }
            if (s == 3) {
                int gr = tr*64 + qrA[j] - 8;          // qr in [8,72) -> [0,64)
                int gc = tc*64 + 4*qcA[j] - 16;       // qc in [4,20) -> [0,64)
                __builtin_nontemporal_store(ou, (f4*)(outu + (size_t)gr*1024 + gc));
                __builtin_nontemporal_store(ov, (f4*)(outv + (size_t)gr*1024 + gc));
            }
        }
        if (s < 3) {
            __syncthreads();   // all reads of t_s done
#pragma unroll
            for (int j = 0; j < NQ; ++j) {
                if (!act[j]) continue;
                *(f4*)(tu+lidx[j]) = stu[j];
                *(f4*)(tv+lidx[j]) = stv[j];
            }
            __syncthreads();   // t_{s+1} visible
        }
    }
}

extern "C" void kernel_launch(void* const* d_in, const int* in_sizes, int n_in,
                              void* d_out, int out_size, void* d_ws, size_t ws_size,
                              hipStream_t stream) {
    const float* h   = (const float*)d_in[0];
    const float* sRe = (const float*)d_in[1];
    const float* sUA = (const float*)d_in[2];
    const float* sUB = (const float*)d_in[3];
    const float* sVA = (const float*)d_in[4];
    const float* sVB = (const float*)d_in[5];
    float* o = (float*)d_out;
    rk4_stencil<<<dim3(16,16,8), dim3(NT,1,1), 0, stream>>>(h, sRe, sUA, sUB, sVA, sVB, o);
}